// Round 10
// baseline (237.033 us; speedup 1.0000x reference)
//
#include <hip/hip_runtime.h>
#include <math.h>

#define SHEET 160
#define LTOT (SHEET*SHEET)          // 25600
#define F_AFF 450
#define F_LAT 625
#define N_ITERS 10
#define IN_HW 174                   // SHEET + AFF_K - 1
#define HOMEO 0.02f
#define PI_D 3.14159265358979323846

// ---- lateral tile geometry: 5 rows x 10 cols of locations per block ----
#define BH 5
#define BW 10
#define BLK 320                     // 5 waves, each handles one row (10 locations)
#define TCOLS (SHEET/BW)            // 16
#define GRID_L ((SHEET/BH)*TCOLS)   // 512 blocks = exactly 2/CU
#define EH 53                       // BH + 48 E-field rows
#define EWH 30                      // 29 data cols per parity half + 1 pad
#define EP_HALF (EH*EWH)            // 1590
#define EP_N (2*EP_HALF)            // 3180
#define LW 64                       // 62 data cols padded to 64 (b128-aligned rows)
#define LH 57                       // BH + 52
#define LT_N (LH*LW)                // 3648

// pre-pass geometry: wave-per-location
#define AWPB 8
#define ABLK (AWPB*64)
#define ANBLK (LTOT/AWPB)           // 3200

#define NPAIR 256                   // packed words per location (4 per lane)

// ---- workspace layout (float offsets) ----
#define WS_SRE    0                 // 32 (25 used)
#define WS_PKF    32                // int[512]  pack-order f index
#define WS_PKL    544               // float[512] pack-order lri
#define WS_OFFT   1056              // int[512]  pack-order gather offset
#define WS_AFFTAB 1568              // float2[512] {env, off}
#define WS_AFF    2592
#define WS_B0     (WS_AFF + LTOT)
#define WS_B1     (WS_B0  + LTOT)
#define WS_LM     (WS_B1  + LTOT)
#define WS_PART   (WS_LM  + LTOT)   // GRID_L floats
#define WS_WQ     (WS_PART + 512)   // 25600*256 u32 = 26.2 MB

// DPP wave-64 sum: result lands in lane 63 (VALU pipe, no LDS traffic)
__device__ __forceinline__ float wred_dpp(float v) {
    v += __int_as_float(__builtin_amdgcn_update_dpp(0, __float_as_int(v), 0x111, 0xf, 0xf, true)); // row_shr:1
    v += __int_as_float(__builtin_amdgcn_update_dpp(0, __float_as_int(v), 0x112, 0xf, 0xf, true)); // row_shr:2
    v += __int_as_float(__builtin_amdgcn_update_dpp(0, __float_as_int(v), 0x114, 0xf, 0xf, true)); // row_shr:4
    v += __int_as_float(__builtin_amdgcn_update_dpp(0, __float_as_int(v), 0x118, 0xf, 0xf, true)); // row_shr:8
    v += __int_as_float(__builtin_amdgcn_update_dpp(0, __float_as_int(v), 0x142, 0xa, 0xf, true)); // bcast15 -> rows 1,3
    v += __int_as_float(__builtin_amdgcn_update_dpp(0, __float_as_int(v), 0x143, 0xc, 0xf, true)); // bcast31 -> rows 2,3
    return v;
}

__device__ __forceinline__ unsigned f2bf(float f) {   // RNE float->bf16 bits
    unsigned u = __float_as_uint(f);
    return (u + 0x7FFFu + ((u >> 16) & 1u)) >> 16;
}

// ---------------- init: constant tables + nz-compacted pack tables ----------------
__global__ __launch_bounds__(1024) void k_init(float* __restrict__ ws) {
    __shared__ float red[1024];
    __shared__ float lriS[640];
    __shared__ int   nzf[512];
    __shared__ int   wcnt[16];
    const int t = threadIdx.x;
    const int lane = t & 63, wvi = t >> 6;

    float sre_raw = 0.f;
    if (t < 25) {
        int u = t / 5, v = t % 5;
        double d = sqrt((double)((u-2)*(u-2) + (v-2)*(v-2)));
        if (d < 2.5) { double cv = cos(fmin(d/5.0, 1.0) * PI_D * 0.5); sre_raw = (float)(cv*cv); }
    }

    float lri_raw = 0.f;
    const int dy = t / 25, dx = t % 25;
    if (t < 625) {
        double d = sqrt((double)((dy-12)*(dy-12) + (dx-12)*(dx-12)));
        double base = 0.0, inh = 0.0;
        if (d < 12.5) { double cv = cos(fmin(d/25.0, 1.0) * PI_D * 0.5); base = cv*cv; }
        if (d < 1.25) { double cv = cos(fmin(d/2.5,  1.0) * PI_D * 0.5); inh  = cv*cv; }
        lri_raw = (float)(base * (1.0 - inh));
    }
    const bool nz = (lri_raw != 0.f);
    if (t < 640) lriS[t] = lri_raw;

    red[t] = lri_raw;
    __syncthreads();
    #pragma unroll
    for (int s = 512; s > 0; s >>= 1) {
        if (t < s) red[t] = fmaxf(red[t], red[t + s]);
        __syncthreads();
    }
    const float lri_max = red[0];
    __syncthreads();

    red[t] = sre_raw;
    __syncthreads();
    #pragma unroll
    for (int s = 512; s > 0; s >>= 1) {
        if (t < s) red[t] += red[t + s];
        __syncthreads();
    }
    const float sre_sum = red[0];

    if (t < 32) ws[WS_SRE + t] = (t < 25) ? sre_raw / sre_sum : 0.f;

    // ---- ballot prefix-scan -> compacted nonzero-lri list ----
    unsigned long long bal = __ballot(nz);
    if (lane == 0) wcnt[wvi] = __popcll(bal);
    __syncthreads();
    int woff = 0, ntot = 0;
    #pragma unroll
    for (int v2 = 0; v2 < 16; ++v2) { int c = wcnt[v2]; if (v2 < wvi) woff += c; ntot += c; }
    if (nz) nzf[woff + __popcll(bal & ((1ull << lane) - 1ull))] = t;
    __syncthreads();

    // pack tables: pair i = t (q = t>>6, lane = t&63), halves h=0,1
    if (t < 256) {
        #pragma unroll
        for (int h = 0; h < 2; ++h) {
            int idx = 2*t + h;
            int f = 624, off = 0; float lv = 0.f;
            if (idx < ntot) {
                f = nzf[idx];
                int fy = f / 25, fx = f - 25*fy;
                off = fy * (2*EWH) + fx;
                lv = lriS[f] / lri_max;
            }
            int slot = (2*(t >> 6) + h)*64 + (t & 63);
            ((int*)  (ws + WS_PKF ))[slot] = f;
            ((float*)(ws + WS_PKL ))[slot] = lv;
            ((int*)  (ws + WS_OFFT))[slot] = off;
        }
    }

    // afferent table: {env, x offset}
    if (t < 512) {
        float ev = 0.f; int off = 0;
        if (t < 450) {
            int c  = t / 225, rr = t % 225;
            int kh = rr / 15, kw = rr % 15;
            double d = sqrt((double)((kh-7)*(kh-7) + (kw-7)*(kw-7)));
            if (d < 7.5) { double cv = cos(fmin(d/15.0, 1.0) * PI_D * 0.5); ev = (float)(cv*cv); }
            off = c * (IN_HW*IN_HW) + kh * IN_HW + kw;
        }
        ((float2*)(ws + WS_AFFTAB))[t] = make_float2(ev, __int_as_float(off));
    }
}

// ---------------- fused afferent + pack: one wave = one location ----------------
__global__ __launch_bounds__(ABLK) void k_pre(const float* __restrict__ x,
                                              const float* __restrict__ rfs,
                                              const float* __restrict__ latw,
                                              const float* __restrict__ ada,
                                              float* __restrict__ out_rawaff,
                                              float* __restrict__ ws,
                                              unsigned* __restrict__ wq) {
    const int w = threadIdx.x >> 6, lane = threadIdx.x & 63;
    const int l = blockIdx.x * AWPB + w;
    const int i = l / SHEET, j = l % SHEET;
    const int xbase = i * IN_HW + j;

    // issue all 18 stream loads; sched_barrier pins them here (forces in-flight MLP)
    const float* rrow = rfs  + (size_t)l * F_AFF;
    const float* wrow = latw + (size_t)l * F_LAT;
    float rv[8], wv[10];
    #pragma unroll
    for (int it = 0; it < 8; ++it) {
        int f = it * 64 + lane;
        rv[it] = rrow[(f < F_AFF) ? f : 0];
    }
    #pragma unroll
    for (int it = 0; it < 10; ++it) {
        int f = it * 64 + lane;
        wv[it] = wrow[(f < F_LAT) ? f : 0];
    }
    __builtin_amdgcn_sched_barrier(0);

    // afferent dot
    const float2* atab = (const float2*)(ws + WS_AFFTAB);
    float dot = 0.f, rsum = 0.f;
    #pragma unroll
    for (int it = 0; it < 8; ++it) {
        int f = it * 64 + lane;
        float2 tb = atab[f];
        float r = (f < F_AFF) ? rv[it] : 0.f;
        float xv = x[xbase + __float_as_int(tb.y)];
        dot = fmaf(xv * tb.x, r, dot);
        rsum += r;
    }
    dot = wred_dpp(dot);
    rsum = wred_dpp(rsum);
    if (lane == 63) {
        float a = dot / rsum;
        out_rawaff[l] = 45.0f * a;                 // raw_aff
        float aff = a - ada[l];
        ws[WS_AFF + l] = aff;
        ws[WS_B0  + l] = fmaxf(aff, 0.f);          // lat_0 = relu(aff)
        ws[WS_LM  + l] = 0.f;
    }

    // lateral sum (exact fp32, all 625)
    float wsum = 0.f;
    #pragma unroll
    for (int it = 0; it < 10; ++it) {
        int f = it * 64 + lane;
        wsum += (f < F_LAT) ? wv[it] : 0.f;
    }
    wsum = wred_dpp(wsum);
    const float inv = 1.0f / __int_as_float(__builtin_amdgcn_readlane(__float_as_int(wsum), 63));

    // pack nonzero-lri entries (gathers hit L1/L2 - row just streamed)
    const int*   pkF = (const int*)  (ws + WS_PKF);
    const float* pkL = (const float*)(ws + WS_PKL);
    unsigned* dst = wq + (size_t)l * NPAIR;
    #pragma unroll
    for (int q = 0; q < 4; ++q) {
        int slo = (2*q)*64 + lane, shi = (2*q+1)*64 + lane;
        float wlo = wrow[pkF[slo]] * pkL[slo] * inv;
        float whi = wrow[pkF[shi]] * pkL[shi] * inv;
        dst[q*64 + lane] = f2bf(wlo) | (f2bf(whi) << 16);
    }
}

// ---------------- lateral iteration: conv(2-row blocked) + segment-reuse dot + DPP reduce ----------------
__global__ __launch_bounds__(BLK, 3) void k_lat(const unsigned* __restrict__ wq,
                                                float* __restrict__ ws,
                                                const float* __restrict__ lsrc,
                                                float* __restrict__ lat_out) {
    __shared__ float Lt[LT_N];
    __shared__ float Ep[EP_N];
    const int b  = blockIdx.x;
    const int i0 = (b / TCOLS) * BH;
    const int j0 = (b % TCOLS) * BW;
    const int tid = threadIdx.x;
    const int w = tid >> 6, lane = tid & 63;
    const int lrow = (i0 + w) * SHEET + j0;        // wave w owns locs lrow+0..9

    // per-lane gather offsets (8 slots)
    const int* offT = (const int*)(ws + WS_OFFT);
    int offr[8];
    #pragma unroll
    for (int q8 = 0; q8 < 8; ++q8) offr[q8] = offT[q8*64 + lane];

    // prefetch all 10 locations' packed weights (latency hidden under stage+conv)
    unsigned wp[10][4];
    #pragma unroll
    for (int s = 0; s < 10; ++s) {
        const unsigned* row = wq + (size_t)(lrow + s) * NPAIR;
        #pragma unroll
        for (int q = 0; q < 4; ++q) wp[s][q] = row[q*64 + lane];
    }
    __builtin_amdgcn_sched_barrier(0);

    // sre (uniform -> SGPRs)
    float sreg[25];
    #pragma unroll
    for (int q = 0; q < 25; ++q) sreg[q] = ws[WS_SRE + q];

    // ---- stage L tile (pad = HOMEO), 57 x 62 in [57][64] ----
    for (int idx = tid; idx < LT_N; idx += BLK) {
        int r = idx >> 6, c = idx & 63;
        int y  = i0 + r - 26;
        int xx = j0 + c - 26;
        float v = HOMEO;
        if (c < 62 && (unsigned)y < SHEET && (unsigned)xx < SHEET) v = lsrc[y*SHEET + xx];
        Lt[idx] = v;
    }
    __syncthreads();

    // ---- 5x5 conv, 2 output rows x 4 cols per item (27 row-pairs x 15 quads) ----
    for (int qi = tid; qi < 27*15; qi += BLK) {
        int rp = qi / 15, q = qi - rp*15;
        int y0 = rp * 2, x0 = q * 4;
        bool has2 = (rp < 26);
        float ra[6][8];
        #pragma unroll
        for (int u = 0; u < 5; ++u) {
            const float* rowp = &Lt[(y0 + u)*LW + x0];
            #pragma unroll
            for (int v = 0; v < 8; ++v) ra[u][v] = rowp[v];
        }
        if (has2) {
            const float* rowp = &Lt[(y0 + 5)*LW + x0];
            #pragma unroll
            for (int v = 0; v < 8; ++v) ra[5][v] = rowp[v];
        } else {
            #pragma unroll
            for (int v = 0; v < 8; ++v) ra[5][v] = 0.f;
        }
        float a0=0.f,a1=0.f,a2=0.f,a3=0.f, c0v=0.f,c1v=0.f,c2v=0.f,c3v=0.f;
        #pragma unroll
        for (int u = 0; u < 5; ++u) {
            #pragma unroll
            for (int v = 0; v < 5; ++v) {
                float sv = sreg[u*5 + v];
                a0  = fmaf(ra[u][v],     sv, a0);
                a1  = fmaf(ra[u][v + 1], sv, a1);
                a2  = fmaf(ra[u][v + 2], sv, a2);
                a3  = fmaf(ra[u][v + 3], sv, a3);
                c0v = fmaf(ra[u+1][v],     sv, c0v);
                c1v = fmaf(ra[u+1][v + 1], sv, c1v);
                c2v = fmaf(ra[u+1][v + 2], sv, c2v);
                c3v = fmaf(ra[u+1][v + 3], sv, c3v);
            }
        }
        int yg = i0 - 24 + y0;
        int xg = j0 - 24 + x0;
        bool x0ok = (unsigned)(xg    ) < SHEET;
        bool x1ok = (unsigned)(xg + 1) < SHEET;
        bool x2ok = (unsigned)(xg + 2) < SHEET;
        bool x3ok = (unsigned)(xg + 3) < SHEET;
        bool y0ok = (unsigned)yg < SHEET;
        int cbase = y0 * EWH + 2*q;
        Ep[cbase]               = (y0ok && x0ok) ? a0 : HOMEO;
        Ep[EP_HALF + cbase]     = (y0ok && x1ok) ? a1 : HOMEO;
        Ep[cbase + 1]           = (y0ok && x2ok) ? a2 : HOMEO;
        Ep[EP_HALF + cbase + 1] = (y0ok && x3ok) ? a3 : HOMEO;
        if (has2) {
            bool y1ok = (unsigned)(yg + 1) < SHEET;
            int cb1 = cbase + EWH;
            Ep[cb1]               = (y1ok && x0ok) ? c0v : HOMEO;
            Ep[EP_HALF + cb1]     = (y1ok && x1ok) ? c1v : HOMEO;
            Ep[cb1 + 1]           = (y1ok && x2ok) ? c2v : HOMEO;
            Ep[EP_HALF + cb1 + 1] = (y1ok && x3ok) ? c3v : HOMEO;
        }
    }
    __syncthreads();

    // ---- dot: segment-register reuse across same-parity locations ----
    float acc[10] = {0.f,0.f,0.f,0.f,0.f,0.f,0.f,0.f,0.f,0.f};
    const int segbase = w * EWH;
    #pragma unroll
    for (int q = 0; q < 4; ++q) {
        float slo[2][5], shi[2][5];
        #pragma unroll
        for (int p = 0; p < 2; ++p) {
            int blo = p*EP_HALF + segbase + offr[2*q];
            int bhi = p*EP_HALF + segbase + offr[2*q + 1];
            #pragma unroll
            for (int c = 0; c < 5; ++c) { slo[p][c] = Ep[blo + c]; shi[p][c] = Ep[bhi + c]; }
        }
        #pragma unroll
        for (int s = 0; s < 10; ++s) {
            unsigned pk = wp[s][q];
            acc[s] = fmaf(slo[s & 1][s >> 1], __uint_as_float(pk << 16),         acc[s]);
            acc[s] = fmaf(shi[s & 1][s >> 1], __uint_as_float(pk & 0xffff0000u), acc[s]);
        }
    }
    #pragma unroll
    for (int s = 0; s < 10; ++s) acc[s] = wred_dpp(acc[s]);

    if (lane == 63) {
        #pragma unroll
        for (int s = 0; s < 10; ++s) {
            int l = lrow + s;
            int gbase = (s & 1)*EP_HALF + segbase + (s >> 1);
            float ec = Ep[gbase + 24*EWH + 12];
            float v = ec * 0.45f - acc[s] * 0.55f + ws[WS_AFF + l];
            v = tanhf(fmaxf(v, 0.f));
            lat_out[l] = v;
            ws[WS_LM + l] += v;
        }
    }
}

// ---------------- hebbian correlation: same dot structure, no conv ----------------
__global__ __launch_bounds__(BLK, 3) void k_hebb(const unsigned* __restrict__ wq,
                                                 float* __restrict__ ws) {
    __shared__ float LMp[EP_N];
    __shared__ float part[5];
    const int b  = blockIdx.x;
    const int i0 = (b / TCOLS) * BH;
    const int j0 = (b % TCOLS) * BW;
    const int tid = threadIdx.x;
    const int w = tid >> 6, lane = tid & 63;
    const int lrow = (i0 + w) * SHEET + j0;
    const float* lm = ws + WS_LM;

    const int* offT = (const int*)(ws + WS_OFFT);
    int offr[8];
    #pragma unroll
    for (int q8 = 0; q8 < 8; ++q8) offr[q8] = offT[q8*64 + lane];

    unsigned wp[10][4];
    #pragma unroll
    for (int s = 0; s < 10; ++s) {
        const unsigned* row = wq + (size_t)(lrow + s) * NPAIR;
        #pragma unroll
        for (int q = 0; q < 4; ++q) wp[s][q] = row[q*64 + lane];
    }
    __builtin_amdgcn_sched_barrier(0);

    // stage lat_mean tile (x0.1, pad HOMEO), parity-split
    for (int idx = tid; idx < EP_N; idx += BLK) {
        int p   = idx / EP_HALF;
        int rem = idx - p * EP_HALF;
        int y   = rem / EWH;
        int col = rem - y * EWH;
        int yg = i0 - 24 + y;
        int xg = j0 - 24 + 2 * col + p;
        float v = HOMEO;
        if ((unsigned)yg < SHEET && (unsigned)xg < SHEET && col < 29) v = lm[yg*SHEET + xg] * 0.1f;
        LMp[idx] = v;
    }
    __syncthreads();

    float acc[10] = {0.f,0.f,0.f,0.f,0.f,0.f,0.f,0.f,0.f,0.f};
    const int segbase = w * EWH;
    #pragma unroll
    for (int q = 0; q < 4; ++q) {
        float slo[2][5], shi[2][5];
        #pragma unroll
        for (int p = 0; p < 2; ++p) {
            int blo = p*EP_HALF + segbase + offr[2*q];
            int bhi = p*EP_HALF + segbase + offr[2*q + 1];
            #pragma unroll
            for (int c = 0; c < 5; ++c) { slo[p][c] = LMp[blo + c]; shi[p][c] = LMp[bhi + c]; }
        }
        #pragma unroll
        for (int s = 0; s < 10; ++s) {
            unsigned pk = wp[s][q];
            acc[s] = fmaf(slo[s & 1][s >> 1], __uint_as_float(pk << 16),         acc[s]);
            acc[s] = fmaf(shi[s & 1][s >> 1], __uint_as_float(pk & 0xffff0000u), acc[s]);
        }
    }
    #pragma unroll
    for (int s = 0; s < 10; ++s) acc[s] = wred_dpp(acc[s]);

    if (lane == 63) {
        float wacc = 0.f;
        #pragma unroll
        for (int s = 0; s < 10; ++s) {
            int gbase = (s & 1)*EP_HALF + segbase + (s >> 1);
            float lmv = LMp[gbase + 24*EWH + 12];      // lat_mean[l] * 0.1
            wacc += lmv * 62.5f * acc[s];
        }
        part[w] = wacc;
    }
    __syncthreads();
    if (tid == 0) {
        float s = 0.f;
        #pragma unroll
        for (int q = 0; q < 5; ++q) s += part[q];
        ws[WS_PART + b] = s;
    }
}

// ---------------- deterministic final reduce ----------------
__global__ __launch_bounds__(512) void k_final(const float* __restrict__ ws,
                                               float* __restrict__ out_scalar) {
    __shared__ float red[512];
    red[threadIdx.x] = ws[WS_PART + threadIdx.x];
    __syncthreads();
    #pragma unroll
    for (int st = 256; st > 0; st >>= 1) {
        if (threadIdx.x < st) red[threadIdx.x] += red[threadIdx.x + st];
        __syncthreads();
    }
    if (threadIdx.x == 0) *out_scalar = red[0];
}

extern "C" void kernel_launch(void* const* d_in, const int* in_sizes, int n_in,
                              void* d_out, int out_size, void* d_ws, size_t ws_size,
                              hipStream_t stream) {
    const float* x    = (const float*)d_in[0];
    const float* rfs  = (const float*)d_in[1];
    const float* latw = (const float*)d_in[2];
    const float* ada  = (const float*)d_in[3];
    float* out = (float*)d_out;
    float* ws  = (float*)d_ws;
    unsigned* wq = (unsigned*)(ws + WS_WQ);

    k_init<<<1, 1024, 0, stream>>>(ws);
    k_pre<<<ANBLK, ABLK, 0, stream>>>(x, rfs, latw, ada, out, ws, wq);

    for (int t = 0; t < N_ITERS; ++t) {
        const float* src = ws + ((t & 1) ? WS_B1 : WS_B0);
        float* dst = (t == N_ITERS - 1) ? (out + LTOT)
                                        : (ws + ((t & 1) ? WS_B0 : WS_B1));
        k_lat<<<GRID_L, BLK, 0, stream>>>(wq, ws, src, dst);
    }

    k_hebb<<<GRID_L, BLK, 0, stream>>>(wq, ws);
    k_final<<<1, 512, 0, stream>>>(ws, out + 2 * LTOT);
}

// Round 11
// 189.213 us; speedup vs baseline: 1.2527x; 1.2527x over previous
//
#include <hip/hip_runtime.h>
#include <math.h>

#define SHEET 160
#define LTOT (SHEET*SHEET)          // 25600
#define F_AFF 450
#define F_LAT 625
#define N_ITERS 10
#define IN_HW 174                   // SHEET + AFF_K - 1
#define HOMEO 0.02f
#define PI_D 3.14159265358979323846

// ---- lateral tile geometry: 10 x 10 locations per block, 1 block/CU ----
#define BH 10
#define BW 10
#define BLK 640                     // 10 waves, each owns one row (10 locations)
#define TCOLS (SHEET/BW)            // 16
#define GRID_L ((SHEET/BH)*TCOLS)   // 16*16 = 256 blocks = exactly 1/CU
#define EH 58                       // BH + 48 E-field rows
#define EWH 30                      // 29 data cols per parity half + 1 pad
#define EP_HALF (EH*EWH)            // 1740
#define EP_N (2*EP_HALF)            // 3480
#define LW 64                       // 62 data cols padded to 64
#define LH 62                       // BH + 52
#define LT_N (LH*LW)                // 3968

// pre-pass geometry: wave-per-location
#define AWPB 8
#define ABLK (AWPB*64)
#define ANBLK (LTOT/AWPB)           // 3200

#define NPAIR 320                   // packed words per location (5 per lane)

// ---- workspace layout (float offsets) ----
#define WS_SRE    0                 // 32 (25 used)
#define WS_LATTAB 32                // float2[640] {lri, off}
#define WS_AFFTAB 1312              // float2[512] {env, off}
#define WS_AFF    2336
#define WS_B0     (WS_AFF + LTOT)
#define WS_B1     (WS_B0  + LTOT)
#define WS_LM     (WS_B1  + LTOT)
#define WS_WQ     (WS_LM  + LTOT + 64)   // 25600*320 u32 = 32.8 MB

// DPP wave-64 sum: result lands in lane 63 (VALU pipe, no LDS traffic)
__device__ __forceinline__ float wred_dpp(float v) {
    v += __int_as_float(__builtin_amdgcn_update_dpp(0, __float_as_int(v), 0x111, 0xf, 0xf, true)); // row_shr:1
    v += __int_as_float(__builtin_amdgcn_update_dpp(0, __float_as_int(v), 0x112, 0xf, 0xf, true)); // row_shr:2
    v += __int_as_float(__builtin_amdgcn_update_dpp(0, __float_as_int(v), 0x114, 0xf, 0xf, true)); // row_shr:4
    v += __int_as_float(__builtin_amdgcn_update_dpp(0, __float_as_int(v), 0x118, 0xf, 0xf, true)); // row_shr:8
    v += __int_as_float(__builtin_amdgcn_update_dpp(0, __float_as_int(v), 0x142, 0xa, 0xf, true)); // bcast15
    v += __int_as_float(__builtin_amdgcn_update_dpp(0, __float_as_int(v), 0x143, 0xc, 0xf, true)); // bcast31
    return v;
}

__device__ __forceinline__ unsigned f2bf(float f) {   // RNE float->bf16 bits
    unsigned u = __float_as_uint(f);
    return (u + 0x7FFFu + ((u >> 16) & 1u)) >> 16;
}

// ---------------- init: constant tables + scalar zero ----------------
__global__ __launch_bounds__(1024) void k_init(float* __restrict__ ws,
                                               float* __restrict__ out) {
    __shared__ float red[1024];
    const int t = threadIdx.x;

    if (t == 0) out[2 * LTOT] = 0.f;   // k_hebb atomicAdds into this

    float sre_raw = 0.f;
    if (t < 25) {
        int u = t / 5, v = t % 5;
        double d = sqrt((double)((u-2)*(u-2) + (v-2)*(v-2)));
        if (d < 2.5) { double cv = cos(fmin(d/5.0, 1.0) * PI_D * 0.5); sre_raw = (float)(cv*cv); }
    }

    float lri_raw = 0.f;
    const int dy = t / 25, dx = t % 25;
    if (t < 625) {
        double d = sqrt((double)((dy-12)*(dy-12) + (dx-12)*(dx-12)));
        double base = 0.0, inh = 0.0;
        if (d < 12.5) { double cv = cos(fmin(d/25.0, 1.0) * PI_D * 0.5); base = cv*cv; }
        if (d < 1.25) { double cv = cos(fmin(d/2.5,  1.0) * PI_D * 0.5); inh  = cv*cv; }
        lri_raw = (float)(base * (1.0 - inh));
    }

    red[t] = lri_raw;
    __syncthreads();
    #pragma unroll
    for (int s = 512; s > 0; s >>= 1) {
        if (t < s) red[t] = fmaxf(red[t], red[t + s]);
        __syncthreads();
    }
    const float lri_max = red[0];
    __syncthreads();

    red[t] = sre_raw;
    __syncthreads();
    #pragma unroll
    for (int s = 512; s > 0; s >>= 1) {
        if (t < s) red[t] += red[t + s];
        __syncthreads();
    }
    const float sre_sum = red[0];

    if (t < 32) ws[WS_SRE + t] = (t < 25) ? sre_raw / sre_sum : 0.f;

    // lateral table: {lri_norm, gather offset dy*(2*EWH)+dx}; lri=0 for t>=625
    if (t < 640) {
        float lv = (t < 625) ? lri_raw / lri_max : 0.f;
        int  off = (t < 625) ? (dy * (2*EWH) + dx) : 0;
        ((float2*)(ws + WS_LATTAB))[t] = make_float2(lv, __int_as_float(off));
    }

    // afferent table: {env, x offset}
    if (t < 512) {
        float ev = 0.f; int off = 0;
        if (t < 450) {
            int c  = t / 225, rr = t % 225;
            int kh = rr / 15, kw = rr % 15;
            double d = sqrt((double)((kh-7)*(kh-7) + (kw-7)*(kw-7)));
            if (d < 7.5) { double cv = cos(fmin(d/15.0, 1.0) * PI_D * 0.5); ev = (float)(cv*cv); }
            off = c * (IN_HW*IN_HW) + kh * IN_HW + kw;
        }
        ((float2*)(ws + WS_AFFTAB))[t] = make_float2(ev, __int_as_float(off));
    }
}

// ---------------- fused afferent + pack: one wave = one location ----------------
__global__ __launch_bounds__(ABLK) void k_pre(const float* __restrict__ x,
                                              const float* __restrict__ rfs,
                                              const float* __restrict__ latw,
                                              const float* __restrict__ ada,
                                              float* __restrict__ out_rawaff,
                                              float* __restrict__ ws,
                                              unsigned* __restrict__ wq) {
    const int w = threadIdx.x >> 6, lane = threadIdx.x & 63;
    const int l = blockIdx.x * AWPB + w;
    const int i = l / SHEET, j = l % SHEET;
    const int xbase = i * IN_HW + j;

    // issue all 18 stream loads up front (nontemporal: streamed once)
    const float* rrow = rfs  + (size_t)l * F_AFF;
    const float* wrow = latw + (size_t)l * F_LAT;
    float rv[8], wv[10];
    #pragma unroll
    for (int it = 0; it < 8; ++it) {
        int f = it * 64 + lane;
        rv[it] = __builtin_nontemporal_load(rrow + ((f < F_AFF) ? f : 0));
    }
    #pragma unroll
    for (int it = 0; it < 10; ++it) {
        int f = it * 64 + lane;
        wv[it] = __builtin_nontemporal_load(wrow + ((f < F_LAT) ? f : 0));
    }
    __builtin_amdgcn_sched_barrier(0);

    // afferent dot
    const float2* atab = (const float2*)(ws + WS_AFFTAB);
    float dot = 0.f, rsum = 0.f;
    #pragma unroll
    for (int it = 0; it < 8; ++it) {
        int f = it * 64 + lane;
        float2 tb = atab[f];
        float r = (f < F_AFF) ? rv[it] : 0.f;
        float xv = x[xbase + __float_as_int(tb.y)];
        dot = fmaf(xv * tb.x, r, dot);
        rsum += r;
    }
    dot = wred_dpp(dot);
    rsum = wred_dpp(rsum);
    if (lane == 63) {
        float a = dot / rsum;
        out_rawaff[l] = 45.0f * a;                 // raw_aff
        float aff = a - ada[l];
        ws[WS_AFF + l] = aff;
        ws[WS_B0  + l] = fmaxf(aff, 0.f);          // lat_0 = relu(aff)
        ws[WS_LM  + l] = 0.f;
    }

    // lateral pack: bf16(w*lri/sum), pair layout (f, f+320)
    const float2* ltab = (const float2*)(ws + WS_LATTAB);
    float tmp[10], wsum = 0.f;
    #pragma unroll
    for (int it = 0; it < 10; ++it) {
        int f = it * 64 + lane;
        float lri = ltab[f].x;                     // 0 for f >= 625
        float v = (f < F_LAT) ? wv[it] : 0.f;
        wsum += v;
        tmp[it] = v * lri;
    }
    wsum = wred_dpp(wsum);
    const float inv = 1.0f / __int_as_float(__builtin_amdgcn_readlane(__float_as_int(wsum), 63));

    unsigned* dst = wq + (size_t)l * NPAIR;
    #pragma unroll
    for (int k = 0; k < 5; ++k) {
        unsigned lo = f2bf(tmp[k]     * inv);
        unsigned hi = f2bf(tmp[k + 5] * inv);
        dst[k * 64 + lane] = lo | (hi << 16);
    }
}

// ---------------- lateral iteration: 10x10 tile, grid 256 = 1 block/CU ----------------
__global__ __launch_bounds__(BLK, 3) void k_lat(const unsigned* __restrict__ wq,
                                                float* __restrict__ ws,
                                                const float* __restrict__ lsrc,
                                                float* __restrict__ lat_out) {
    __shared__ float Lt[LT_N];
    __shared__ float Ep[EP_N];
    const int b  = blockIdx.x;
    const int i0 = (b / TCOLS) * BH;
    const int j0 = (b % TCOLS) * BW;
    const int tid = threadIdx.x;
    const int w = tid >> 6, lane = tid & 63;
    const int lrow = (i0 + w) * SHEET + j0;        // wave w owns locs lrow+0..9

    // gather-offset table (per-lane registers)
    const float2* tab = (const float2*)(ws + WS_LATTAB);
    int off_reg[10];
    #pragma unroll
    for (int it = 0; it < 10; ++it) off_reg[it] = __float_as_int(tab[it * 64 + lane].y);

    // prefetch all 10 locations' packed weights (hidden under stage+conv)
    unsigned wp[10][5];
    #pragma unroll
    for (int s = 0; s < 10; ++s) {
        const unsigned* row = wq + (size_t)(lrow + s) * NPAIR;
        #pragma unroll
        for (int k = 0; k < 5; ++k) wp[s][k] = row[k * 64 + lane];
    }
    __builtin_amdgcn_sched_barrier(0);

    // sre (uniform -> scalar loads)
    float sreg[25];
    #pragma unroll
    for (int q = 0; q < 25; ++q) sreg[q] = ws[WS_SRE + q];

    // ---- stage L tile (pad = HOMEO), 62 rows x 62 cols in [62][64] ----
    for (int idx = tid; idx < LT_N; idx += BLK) {
        int r = idx >> 6, c = idx & 63;
        int y  = i0 + r - 26;
        int xx = j0 + c - 26;
        float v = HOMEO;
        if (c < 62 && (unsigned)y < SHEET && (unsigned)xx < SHEET) v = lsrc[y*SHEET + xx];
        Lt[idx] = v;
    }
    __syncthreads();

    // ---- 5x5 conv -> E field 58x58 (4-wide register blocked, parity-split store) ----
    for (int qi = tid; qi < EH * 15; qi += BLK) {
        int y = qi / 15, q = qi - y * 15;
        int x0 = q * 4;
        float a0 = 0.f, a1 = 0.f, a2 = 0.f, a3 = 0.f;
        #pragma unroll
        for (int u = 0; u < 5; ++u) {
            const float* row = &Lt[(y + u) * LW + x0];
            float ra[8];
            #pragma unroll
            for (int v = 0; v < 8; ++v) ra[v] = row[v];
            #pragma unroll
            for (int v = 0; v < 5; ++v) {
                float s = sreg[u * 5 + v];
                a0 = fmaf(ra[v],     s, a0);
                a1 = fmaf(ra[v + 1], s, a1);
                a2 = fmaf(ra[v + 2], s, a2);
                a3 = fmaf(ra[v + 3], s, a3);
            }
        }
        int yg = i0 - 24 + y;
        bool yok = (unsigned)yg < SHEET;
        int xg = j0 - 24 + x0;
        float v0 = (yok && (unsigned)(xg    ) < SHEET) ? a0 : HOMEO;
        float v1 = (yok && (unsigned)(xg + 1) < SHEET) ? a1 : HOMEO;
        float v2 = (yok && (unsigned)(xg + 2) < SHEET) ? a2 : HOMEO;
        float v3 = (yok && (unsigned)(xg + 3) < SHEET) ? a3 : HOMEO;
        int c0 = y * EWH + 2 * q;
        Ep[c0]               = v0;   // E cols 58/59 (q=14) land in the pad
        Ep[EP_HALF + c0]     = v1;   // slot (col 29) - never gathered
        Ep[c0 + 1]           = v2;
        Ep[EP_HALF + c0 + 1] = v3;
    }
    __syncthreads();

    // ---- per-location 625-dot from register-resident bf16 weights ----
    float acc[10];
    #pragma unroll
    for (int s = 0; s < 10; ++s) {
        const int gbase = (s & 1) * EP_HALF + w * EWH + (s >> 1);
        float a = 0.f;
        #pragma unroll
        for (int k = 0; k < 5; ++k) {
            unsigned p = wp[s][k];
            float e0 = Ep[gbase + off_reg[k]];
            float e1 = Ep[gbase + off_reg[k + 5]];
            a = fmaf(e0, __uint_as_float(p << 16),         a);
            a = fmaf(e1, __uint_as_float(p & 0xffff0000u), a);
        }
        acc[s] = a;
    }
    #pragma unroll
    for (int s = 0; s < 10; ++s) acc[s] = wred_dpp(acc[s]);

    if (lane == 63) {
        #pragma unroll
        for (int s = 0; s < 10; ++s) {
            int l = lrow + s;
            int gbase = (s & 1) * EP_HALF + w * EWH + (s >> 1);
            float ec = Ep[gbase + 24*EWH + 12];
            float v = ec * 0.45f - acc[s] * 0.55f + ws[WS_AFF + l];
            v = tanhf(fmaxf(v, 0.f));
            lat_out[l] = v;
            ws[WS_LM + l] += v;
        }
    }
}

// ---------------- hebbian correlation: same 10x10 tiling, no conv, atomic sum ----------------
__global__ __launch_bounds__(BLK, 3) void k_hebb(const unsigned* __restrict__ wq,
                                                 float* __restrict__ ws,
                                                 float* __restrict__ out_scalar) {
    __shared__ float LMp[EP_N];
    __shared__ float part[10];
    const int b  = blockIdx.x;
    const int i0 = (b / TCOLS) * BH;
    const int j0 = (b % TCOLS) * BW;
    const int tid = threadIdx.x;
    const int w = tid >> 6, lane = tid & 63;
    const int lrow = (i0 + w) * SHEET + j0;
    const float* lm = ws + WS_LM;

    const float2* tab = (const float2*)(ws + WS_LATTAB);
    int off_reg[10];
    #pragma unroll
    for (int it = 0; it < 10; ++it) off_reg[it] = __float_as_int(tab[it * 64 + lane].y);

    unsigned wp[10][5];
    #pragma unroll
    for (int s = 0; s < 10; ++s) {
        const unsigned* row = wq + (size_t)(lrow + s) * NPAIR;
        #pragma unroll
        for (int k = 0; k < 5; ++k) wp[s][k] = row[k * 64 + lane];
    }
    __builtin_amdgcn_sched_barrier(0);

    // stage lat_mean tile (x0.1, pad HOMEO), parity-split 58x58
    for (int idx = tid; idx < EP_N; idx += BLK) {
        int p   = idx / EP_HALF;
        int rem = idx - p * EP_HALF;
        int y   = rem / EWH;
        int col = rem - y * EWH;
        int yg = i0 - 24 + y;
        int xg = j0 - 24 + 2 * col + p;
        float v = HOMEO;
        if ((unsigned)yg < SHEET && (unsigned)xg < SHEET && col < 29) v = lm[yg*SHEET + xg] * 0.1f;
        LMp[idx] = v;
    }
    __syncthreads();

    float acc[10];
    #pragma unroll
    for (int s = 0; s < 10; ++s) {
        const int gbase = (s & 1) * EP_HALF + w * EWH + (s >> 1);
        float a = 0.f;
        #pragma unroll
        for (int k = 0; k < 5; ++k) {
            unsigned p = wp[s][k];
            float e0 = LMp[gbase + off_reg[k]];
            float e1 = LMp[gbase + off_reg[k + 5]];
            a = fmaf(e0, __uint_as_float(p << 16),         a);
            a = fmaf(e1, __uint_as_float(p & 0xffff0000u), a);
        }
        acc[s] = a;
    }
    #pragma unroll
    for (int s = 0; s < 10; ++s) acc[s] = wred_dpp(acc[s]);

    if (lane == 63) {
        float wacc = 0.f;
        #pragma unroll
        for (int s = 0; s < 10; ++s) {
            int gbase = (s & 1) * EP_HALF + w * EWH + (s >> 1);
            float lmv = LMp[gbase + 24*EWH + 12];      // lat_mean[l] * 0.1
            wacc += lmv * 62.5f * acc[s];
        }
        part[w] = wacc;
    }
    __syncthreads();
    if (tid == 0) {
        float s = 0.f;
        #pragma unroll
        for (int q = 0; q < 10; ++q) s += part[q];
        atomicAdd(out_scalar, s);
    }
}

extern "C" void kernel_launch(void* const* d_in, const int* in_sizes, int n_in,
                              void* d_out, int out_size, void* d_ws, size_t ws_size,
                              hipStream_t stream) {
    const float* x    = (const float*)d_in[0];
    const float* rfs  = (const float*)d_in[1];
    const float* latw = (const float*)d_in[2];
    const float* ada  = (const float*)d_in[3];
    float* out = (float*)d_out;
    float* ws  = (float*)d_ws;
    unsigned* wq = (unsigned*)(ws + WS_WQ);

    k_init<<<1, 1024, 0, stream>>>(ws, out);
    k_pre<<<ANBLK, ABLK, 0, stream>>>(x, rfs, latw, ada, out, ws, wq);

    for (int t = 0; t < N_ITERS; ++t) {
        const float* src = ws + ((t & 1) ? WS_B1 : WS_B0);
        float* dst = (t == N_ITERS - 1) ? (out + LTOT)
                                        : (ws + ((t & 1) ? WS_B0 : WS_B1));
        k_lat<<<GRID_L, BLK, 0, stream>>>(wq, ws, src, dst);
    }

    k_hebb<<<GRID_L, BLK, 0, stream>>>(wq, ws, out + 2 * LTOT);
}

// Round 13
// 161.805 us; speedup vs baseline: 1.4649x; 1.1694x over previous
//
#include <hip/hip_runtime.h>
#include <math.h>

#define SHEET 160
#define LTOT (SHEET*SHEET)          // 25600
#define F_AFF 450
#define F_LAT 625
#define N_ITERS 10
#define IN_HW 174                   // SHEET + AFF_K - 1
#define HOMEO 0.02f
#define PI_D 3.14159265358979323846

typedef float f32x4 __attribute__((ext_vector_type(4)));

// ---- lateral tile geometry: 10 x 10 locations per block, 1 block/CU ----
#define BH 10
#define BW 10
#define BLK 640                     // 10 waves, each owns one row (10 locations)
#define TCOLS (SHEET/BW)            // 16
#define GRID_L ((SHEET/BH)*TCOLS)   // 256 blocks = exactly 1/CU
#define EH 58                       // BH + 48 E-field rows
#define EWH 30                      // 29 data cols per parity half + 1 pad
#define EP_HALF (EH*EWH)            // 1740
#define EP_N (2*EP_HALF)            // 3480
#define LW 64                       // 62 data cols padded to 64
#define LH 62                       // BH + 52
#define LT_N (LH*LW)                // 3968

// pre-pass geometry: 256-thread blocks, 16 rows each, role-split grid
#define PBLK 256
#define RPB 16
#define NABLK (LTOT/RPB)            // 1600 blocks per role

#define NPAIR 256                   // packed words per location (4 per lane, nz-compacted)

// ---- workspace layout (float offsets) ----
#define WS_SRE    0                 // 32 (25 used)
#define WS_PKF    32                // int[512]   pack-order f index
#define WS_PKL    544               // float[512] pack-order lri
#define WS_OFFT   1056              // int[512]   pack-order gather offset
#define WS_AFFTAB 1568              // float2[512] {env, off}
#define WS_AFF    2592
#define WS_B0     (WS_AFF + LTOT)
#define WS_B1     (WS_B0  + LTOT)
#define WS_LM     (WS_B1  + LTOT)
#define WS_WQ     (WS_LM  + LTOT + 64)   // 25600*256 u32 = 26.2 MB

// DPP wave-64 sum: result lands in lane 63 (VALU pipe, no LDS traffic)
__device__ __forceinline__ float wred_dpp(float v) {
    v += __int_as_float(__builtin_amdgcn_update_dpp(0, __float_as_int(v), 0x111, 0xf, 0xf, true)); // row_shr:1
    v += __int_as_float(__builtin_amdgcn_update_dpp(0, __float_as_int(v), 0x112, 0xf, 0xf, true)); // row_shr:2
    v += __int_as_float(__builtin_amdgcn_update_dpp(0, __float_as_int(v), 0x114, 0xf, 0xf, true)); // row_shr:4
    v += __int_as_float(__builtin_amdgcn_update_dpp(0, __float_as_int(v), 0x118, 0xf, 0xf, true)); // row_shr:8
    v += __int_as_float(__builtin_amdgcn_update_dpp(0, __float_as_int(v), 0x142, 0xa, 0xf, true)); // bcast15
    v += __int_as_float(__builtin_amdgcn_update_dpp(0, __float_as_int(v), 0x143, 0xc, 0xf, true)); // bcast31
    return v;
}

__device__ __forceinline__ unsigned f2bf(float f) {   // RNE float->bf16 bits
    unsigned u = __float_as_uint(f);
    return (u + 0x7FFFu + ((u >> 16) & 1u)) >> 16;
}

// ---------------- init: constant tables + nz-compacted pack tables + scalar zero ----------------
__global__ __launch_bounds__(1024) void k_init(float* __restrict__ ws,
                                               float* __restrict__ out) {
    __shared__ float red[1024];
    __shared__ float lriS[640];
    __shared__ int   nzf[512];
    __shared__ int   wcnt[16];
    const int t = threadIdx.x;
    const int lane = t & 63, wvi = t >> 6;

    if (t == 0) out[2 * LTOT] = 0.f;   // k_hebb atomicAdds into this

    float sre_raw = 0.f;
    if (t < 25) {
        int u = t / 5, v = t % 5;
        double d = sqrt((double)((u-2)*(u-2) + (v-2)*(v-2)));
        if (d < 2.5) { double cv = cos(fmin(d/5.0, 1.0) * PI_D * 0.5); sre_raw = (float)(cv*cv); }
    }

    float lri_raw = 0.f;
    const int dy = t / 25, dx = t % 25;
    if (t < 625) {
        double d = sqrt((double)((dy-12)*(dy-12) + (dx-12)*(dx-12)));
        double base = 0.0, inh = 0.0;
        if (d < 12.5) { double cv = cos(fmin(d/25.0, 1.0) * PI_D * 0.5); base = cv*cv; }
        if (d < 1.25) { double cv = cos(fmin(d/2.5,  1.0) * PI_D * 0.5); inh  = cv*cv; }
        lri_raw = (float)(base * (1.0 - inh));
    }
    const bool nz = (lri_raw != 0.f);
    if (t < 640) lriS[t] = lri_raw;

    red[t] = lri_raw;
    __syncthreads();
    #pragma unroll
    for (int s = 512; s > 0; s >>= 1) {
        if (t < s) red[t] = fmaxf(red[t], red[t + s]);
        __syncthreads();
    }
    const float lri_max = red[0];
    __syncthreads();

    red[t] = sre_raw;
    __syncthreads();
    #pragma unroll
    for (int s = 512; s > 0; s >>= 1) {
        if (t < s) red[t] += red[t + s];
        __syncthreads();
    }
    const float sre_sum = red[0];

    if (t < 32) ws[WS_SRE + t] = (t < 25) ? sre_raw / sre_sum : 0.f;

    // ---- ballot prefix-scan -> compacted nonzero-lri list (488 entries) ----
    unsigned long long bal = __ballot(nz);
    if (lane == 0) wcnt[wvi] = __popcll(bal);
    __syncthreads();
    int woff = 0, ntot = 0;
    #pragma unroll
    for (int v2 = 0; v2 < 16; ++v2) { int c = wcnt[v2]; if (v2 < wvi) woff += c; ntot += c; }
    if (nz) nzf[woff + __popcll(bal & ((1ull << lane) - 1ull))] = t;
    __syncthreads();

    // pack tables: slot (2q+h)*64+lane <- nzf[2*(q*64+lane)+h]
    if (t < 256) {
        #pragma unroll
        for (int h = 0; h < 2; ++h) {
            int idx = 2*t + h;
            int f = 624, off = 0; float lv = 0.f;
            if (idx < ntot) {
                f = nzf[idx];
                int fy = f / 25, fx = f - 25*fy;
                off = fy * (2*EWH) + fx;
                lv = lriS[f] / lri_max;
            }
            int slot = (2*(t >> 6) + h)*64 + (t & 63);
            ((int*)  (ws + WS_PKF ))[slot] = f;
            ((float*)(ws + WS_PKL ))[slot] = lv;
            ((int*)  (ws + WS_OFFT))[slot] = off;
        }
    }

    // afferent table: {env, x offset}
    if (t < 512) {
        float ev = 0.f; int off = 0;
        if (t < 450) {
            int c  = t / 225, rr = t % 225;
            int kh = rr / 15, kw = rr % 15;
            double d = sqrt((double)((kh-7)*(kh-7) + (kw-7)*(kw-7)));
            if (d < 7.5) { double cv = cos(fmin(d/15.0, 1.0) * PI_D * 0.5); ev = (float)(cv*cv); }
            off = c * (IN_HW*IN_HW) + kh * IN_HW + kw;
        }
        ((float2*)(ws + WS_AFFTAB))[t] = make_float2(ev, __int_as_float(off));
    }
}

// ---------------- pre-pass: float4-staged streaming (deep MLP), role-split grid ----------------
// blocks [0, NABLK): afferent (rfs).  blocks [NABLK, 2*NABLK): latw pack.
__global__ __launch_bounds__(PBLK, 4) void k_pre(const float* __restrict__ x,
                                                 const float* __restrict__ rfs,
                                                 const float* __restrict__ latw,
                                                 const float* __restrict__ ada,
                                                 float* __restrict__ out_rawaff,
                                                 float* __restrict__ ws,
                                                 unsigned* __restrict__ wq) {
    __shared__ __align__(16) float S[10016];   // 40 KB: pack 10000, aff 7200
    const int tid = threadIdx.x;
    const int w = tid >> 6, lane = tid & 63;

    if (blockIdx.x < NABLK) {
        // ---- afferent role: stage 16 rows of rfs (1800 float4, 8 indep loads/thread) ----
        const int l0 = blockIdx.x * RPB;
        const f32x4* src4 = (const f32x4*)(rfs + (size_t)l0 * F_AFF);
        #pragma unroll
        for (int k = 0; k < 8; ++k) {
            int idx = k * PBLK + tid;
            if (idx < 1800) ((f32x4*)S)[idx] = __builtin_nontemporal_load(src4 + idx);
        }

        // hoist afferent table into regs (shared across the wave's 4 rows)
        float envA[8]; int offA[8];
        const float2* atab = (const float2*)(ws + WS_AFFTAB);
        #pragma unroll
        for (int it = 0; it < 8; ++it) {
            float2 tb = atab[it*64 + lane];
            envA[it] = tb.x; offA[it] = __float_as_int(tb.y);
        }
        __syncthreads();

        #pragma unroll
        for (int s = 0; s < 4; ++s) {
            const int row = 4*w + s, l = l0 + row;
            const int i = l / SHEET, j = l % SHEET;
            const int xbase = i * IN_HW + j;
            const float* Srow = S + row * F_AFF;
            float dot = 0.f, rs = 0.f;
            #pragma unroll
            for (int it = 0; it < 8; ++it) {
                int f = it*64 + lane;
                float r = (f < F_AFF) ? Srow[f] : 0.f;
                float xv = x[xbase + offA[it]];
                dot = fmaf(xv * envA[it], r, dot);
                rs += r;
            }
            dot = wred_dpp(dot); rs = wred_dpp(rs);
            if (lane == 63) {
                float a = dot / rs;
                out_rawaff[l] = 45.0f * a;             // raw_aff
                float aff = a - ada[l];
                ws[WS_AFF + l] = aff;
                ws[WS_B0  + l] = fmaxf(aff, 0.f);      // lat_0 = relu(aff)
                ws[WS_LM  + l] = 0.f;
            }
        }
    } else {
        // ---- pack role: stage 16 rows of latw (2500 float4, 10 indep loads/thread) ----
        const int l0 = (blockIdx.x - NABLK) * RPB;
        const f32x4* src4 = (const f32x4*)(latw + (size_t)l0 * F_LAT);
        #pragma unroll
        for (int k = 0; k < 10; ++k) {
            int idx = k * PBLK + tid;
            if (idx < 2500) ((f32x4*)S)[idx] = __builtin_nontemporal_load(src4 + idx);
        }

        // hoist pack tables into regs
        int pf[8]; float pl[8];
        #pragma unroll
        for (int q8 = 0; q8 < 8; ++q8) {
            pf[q8] = ((const int*)  (ws + WS_PKF))[q8*64 + lane];
            pl[q8] = ((const float*)(ws + WS_PKL))[q8*64 + lane];
        }
        __syncthreads();

        #pragma unroll
        for (int s = 0; s < 4; ++s) {
            const int row = 4*w + s, l = l0 + row;
            const float* Srow = S + row * F_LAT;
            float sum = 0.f;
            #pragma unroll
            for (int it = 0; it < 10; ++it) {
                int f = it*64 + lane;
                sum += (f < F_LAT) ? Srow[f] : 0.f;
            }
            sum = wred_dpp(sum);
            const float inv = 1.0f / __int_as_float(__builtin_amdgcn_readlane(__float_as_int(sum), 63));
            unsigned* dst = wq + (size_t)l * NPAIR;
            #pragma unroll
            for (int q = 0; q < 4; ++q) {
                unsigned lo = f2bf(Srow[pf[2*q]]     * pl[2*q]     * inv);
                unsigned hi = f2bf(Srow[pf[2*q + 1]] * pl[2*q + 1] * inv);
                dst[q*64 + lane] = lo | (hi << 16);
            }
        }
    }
}

// ---------------- lateral iteration: 10x10 tile, grid 256 = 1 block/CU ----------------
__global__ __launch_bounds__(BLK, 3) void k_lat(const unsigned* __restrict__ wq,
                                                float* __restrict__ ws,
                                                const float* __restrict__ lsrc,
                                                float* __restrict__ lat_out) {
    __shared__ float Lt[LT_N];
    __shared__ float Ep[EP_N];
    const int b  = blockIdx.x;
    const int i0 = (b / TCOLS) * BH;
    const int j0 = (b % TCOLS) * BW;
    const int tid = threadIdx.x;
    const int w = tid >> 6, lane = tid & 63;
    const int lrow = (i0 + w) * SHEET + j0;        // wave w owns locs lrow+0..9

    // per-lane gather offsets (8 compacted slots)
    const int* offT = (const int*)(ws + WS_OFFT);
    int offr[8];
    #pragma unroll
    for (int q8 = 0; q8 < 8; ++q8) offr[q8] = offT[q8*64 + lane];

    // prefetch all 10 locations' packed weights (hidden under stage+conv)
    unsigned wp[10][4];
    #pragma unroll
    for (int s = 0; s < 10; ++s) {
        const unsigned* row = wq + (size_t)(lrow + s) * NPAIR;
        #pragma unroll
        for (int k = 0; k < 4; ++k) wp[s][k] = row[k*64 + lane];
    }
    __builtin_amdgcn_sched_barrier(0);

    // sre (uniform -> scalar loads)
    float sreg[25];
    #pragma unroll
    for (int q = 0; q < 25; ++q) sreg[q] = ws[WS_SRE + q];

    // ---- stage L tile (pad = HOMEO), 62 rows x 62 cols in [62][64] ----
    for (int idx = tid; idx < LT_N; idx += BLK) {
        int r = idx >> 6, c = idx & 63;
        int y  = i0 + r - 26;
        int xx = j0 + c - 26;
        float v = HOMEO;
        if (c < 62 && (unsigned)y < SHEET && (unsigned)xx < SHEET) v = lsrc[y*SHEET + xx];
        Lt[idx] = v;
    }
    __syncthreads();

    // ---- 5x5 conv -> E field 58x58 (4-wide register blocked, parity-split store) ----
    for (int qi = tid; qi < EH * 15; qi += BLK) {
        int y = qi / 15, q = qi - y * 15;
        int x0 = q * 4;
        float a0 = 0.f, a1 = 0.f, a2 = 0.f, a3 = 0.f;
        #pragma unroll
        for (int u = 0; u < 5; ++u) {
            const float* row = &Lt[(y + u) * LW + x0];
            float ra[8];
            #pragma unroll
            for (int v = 0; v < 8; ++v) ra[v] = row[v];
            #pragma unroll
            for (int v = 0; v < 5; ++v) {
                float s = sreg[u * 5 + v];
                a0 = fmaf(ra[v],     s, a0);
                a1 = fmaf(ra[v + 1], s, a1);
                a2 = fmaf(ra[v + 2], s, a2);
                a3 = fmaf(ra[v + 3], s, a3);
            }
        }
        int yg = i0 - 24 + y;
        bool yok = (unsigned)yg < SHEET;
        int xg = j0 - 24 + x0;
        float v0 = (yok && (unsigned)(xg    ) < SHEET) ? a0 : HOMEO;
        float v1 = (yok && (unsigned)(xg + 1) < SHEET) ? a1 : HOMEO;
        float v2 = (yok && (unsigned)(xg + 2) < SHEET) ? a2 : HOMEO;
        float v3 = (yok && (unsigned)(xg + 3) < SHEET) ? a3 : HOMEO;
        int c0 = y * EWH + 2 * q;
        Ep[c0]               = v0;   // E cols 58/59 (q=14) land in the pad
        Ep[EP_HALF + c0]     = v1;   // slot (col 29) - never gathered
        Ep[c0 + 1]           = v2;
        Ep[EP_HALF + c0 + 1] = v3;
    }
    __syncthreads();

    // ---- per-location 625-dot from register-resident bf16 weights ----
    float acc[10];
    #pragma unroll
    for (int s = 0; s < 10; ++s) {
        const int gbase = (s & 1) * EP_HALF + w * EWH + (s >> 1);
        float a = 0.f;
        #pragma unroll
        for (int k = 0; k < 4; ++k) {
            unsigned p = wp[s][k];
            float e0 = Ep[gbase + offr[2*k]];
            float e1 = Ep[gbase + offr[2*k + 1]];
            a = fmaf(e0, __uint_as_float(p << 16),         a);
            a = fmaf(e1, __uint_as_float(p & 0xffff0000u), a);
        }
        acc[s] = a;
    }
    #pragma unroll
    for (int s = 0; s < 10; ++s) acc[s] = wred_dpp(acc[s]);

    if (lane == 63) {
        #pragma unroll
        for (int s = 0; s < 10; ++s) {
            int l = lrow + s;
            int gbase = (s & 1) * EP_HALF + w * EWH + (s >> 1);
            float ec = Ep[gbase + 24*EWH + 12];
            float v = ec * 0.45f - acc[s] * 0.55f + ws[WS_AFF + l];
            v = tanhf(fmaxf(v, 0.f));
            lat_out[l] = v;
            ws[WS_LM + l] += v;
        }
    }
}

// ---------------- hebbian correlation: same 10x10 tiling, no conv, atomic sum ----------------
__global__ __launch_bounds__(BLK, 3) void k_hebb(const unsigned* __restrict__ wq,
                                                 float* __restrict__ ws,
                                                 float* __restrict__ out_scalar) {
    __shared__ float LMp[EP_N];
    __shared__ float part[10];
    const int b  = blockIdx.x;
    const int i0 = (b / TCOLS) * BH;
    const int j0 = (b % TCOLS) * BW;
    const int tid = threadIdx.x;
    const int w = tid >> 6, lane = tid & 63;
    const int lrow = (i0 + w) * SHEET + j0;
    const float* lm = ws + WS_LM;

    const int* offT = (const int*)(ws + WS_OFFT);
    int offr[8];
    #pragma unroll
    for (int q8 = 0; q8 < 8; ++q8) offr[q8] = offT[q8*64 + lane];

    unsigned wp[10][4];
    #pragma unroll
    for (int s = 0; s < 10; ++s) {
        const unsigned* row = wq + (size_t)(lrow + s) * NPAIR;
        #pragma unroll
        for (int k = 0; k < 4; ++k) wp[s][k] = row[k*64 + lane];
    }
    __builtin_amdgcn_sched_barrier(0);

    // stage lat_mean tile (x0.1, pad HOMEO), parity-split 58x58
    for (int idx = tid; idx < EP_N; idx += BLK) {
        int p   = idx / EP_HALF;
        int rem = idx - p * EP_HALF;
        int y   = rem / EWH;
        int col = rem - y * EWH;
        int yg = i0 - 24 + y;
        int xg = j0 - 24 + 2 * col + p;
        float v = HOMEO;
        if ((unsigned)yg < SHEET && (unsigned)xg < SHEET && col < 29) v = lm[yg*SHEET + xg] * 0.1f;
        LMp[idx] = v;
    }
    __syncthreads();

    float acc[10];
    #pragma unroll
    for (int s = 0; s < 10; ++s) {
        const int gbase = (s & 1) * EP_HALF + w * EWH + (s >> 1);
        float a = 0.f;
        #pragma unroll
        for (int k = 0; k < 4; ++k) {
            unsigned p = wp[s][k];
            float e0 = LMp[gbase + offr[2*k]];
            float e1 = LMp[gbase + offr[2*k + 1]];
            a = fmaf(e0, __uint_as_float(p << 16),         a);
            a = fmaf(e1, __uint_as_float(p & 0xffff0000u), a);
        }
        acc[s] = a;
    }
    #pragma unroll
    for (int s = 0; s < 10; ++s) acc[s] = wred_dpp(acc[s]);

    if (lane == 63) {
        float wacc = 0.f;
        #pragma unroll
        for (int s = 0; s < 10; ++s) {
            int gbase = (s & 1) * EP_HALF + w * EWH + (s >> 1);
            float lmv = LMp[gbase + 24*EWH + 12];      // lat_mean[l] * 0.1
            wacc += lmv * 62.5f * acc[s];
        }
        part[w] = wacc;
    }
    __syncthreads();
    if (tid == 0) {
        float s = 0.f;
        #pragma unroll
        for (int q = 0; q < 10; ++q) s += part[q];
        atomicAdd(out_scalar, s);
    }
}

extern "C" void kernel_launch(void* const* d_in, const int* in_sizes, int n_in,
                              void* d_out, int out_size, void* d_ws, size_t ws_size,
                              hipStream_t stream) {
    const float* x    = (const float*)d_in[0];
    const float* rfs  = (const float*)d_in[1];
    const float* latw = (const float*)d_in[2];
    const float* ada  = (const float*)d_in[3];
    float* out = (float*)d_out;
    float* ws  = (float*)d_ws;
    unsigned* wq = (unsigned*)(ws + WS_WQ);

    k_init<<<1, 1024, 0, stream>>>(ws, out);
    k_pre<<<2 * NABLK, PBLK, 0, stream>>>(x, rfs, latw, ada, out, ws, wq);

    for (int t = 0; t < N_ITERS; ++t) {
        const float* src = ws + ((t & 1) ? WS_B1 : WS_B0);
        float* dst = (t == N_ITERS - 1) ? (out + LTOT)
                                        : (ws + ((t & 1) ? WS_B0 : WS_B1));
        k_lat<<<GRID_L, BLK, 0, stream>>>(wq, ws, src, dst);
    }

    k_hebb<<<GRID_L, BLK, 0, stream>>>(wq, ws, out + 2 * LTOT);
}

// Round 14
// 136.195 us; speedup vs baseline: 1.7404x; 1.1880x over previous
//
#include <hip/hip_runtime.h>
#include <math.h>

#define SHEET 160
#define LTOT (SHEET*SHEET)          // 25600
#define F_AFF 450
#define F_LAT 625
#define N_ITERS 10
#define IN_HW 174                   // SHEET + AFF_K - 1
#define HOMEO 0.02f
#define PI_D 3.14159265358979323846

typedef float f32x4 __attribute__((ext_vector_type(4)));

// ---- lateral tile geometry: 10 x 10 locations per block, 1 block/CU ----
#define BH 10
#define BW 10
#define BLK 640                     // 10 waves, each owns one row (10 locations)
#define TCOLS (SHEET/BW)            // 16
#define GRID_L ((SHEET/BH)*TCOLS)   // 256 blocks = exactly 1/CU
#define EH 58                       // BH + 48 E-field rows
#define EWH 30                      // 29 data cols per parity half + 1 pad
#define EP_HALF (EH*EWH)            // 1740
#define EP_N (2*EP_HALF)            // 3480
#define LW 64                       // 62 data cols padded to 64
#define LH 62                       // BH + 52
#define LT_N (LH*LW)                // 3968

// pre-pass geometry: 256-thread blocks, 8 rows each, role-split grid
#define PBLK 256
#define RPB 8
#define NABLK (LTOT/RPB)            // 3200 blocks per role

#define NPAIR 256                   // packed words per location (4 per lane, nz-compacted)

// ---- workspace layout (float offsets) ----
#define WS_SRE    0                 // 32 (25 used)
#define WS_PKF    32                // int[512]   pack-order f index
#define WS_PKL    544               // float[512] pack-order lri
#define WS_OFFT   1056              // int[512]   pack-order gather offset
#define WS_AFFTAB 1568              // float2[512] {env, off}
#define WS_AFF    2592
#define WS_B0     (WS_AFF + LTOT)
#define WS_B1     (WS_B0  + LTOT)
#define WS_LM     (WS_B1  + LTOT)
#define WS_WQ     (WS_LM  + LTOT + 64)   // 25600*256 u32 = 26.2 MB

// DPP wave-64 sum: result lands in lane 63 (VALU pipe, no LDS traffic)
__device__ __forceinline__ float wred_dpp(float v) {
    v += __int_as_float(__builtin_amdgcn_update_dpp(0, __float_as_int(v), 0x111, 0xf, 0xf, true)); // row_shr:1
    v += __int_as_float(__builtin_amdgcn_update_dpp(0, __float_as_int(v), 0x112, 0xf, 0xf, true)); // row_shr:2
    v += __int_as_float(__builtin_amdgcn_update_dpp(0, __float_as_int(v), 0x114, 0xf, 0xf, true)); // row_shr:4
    v += __int_as_float(__builtin_amdgcn_update_dpp(0, __float_as_int(v), 0x118, 0xf, 0xf, true)); // row_shr:8
    v += __int_as_float(__builtin_amdgcn_update_dpp(0, __float_as_int(v), 0x142, 0xa, 0xf, true)); // bcast15
    v += __int_as_float(__builtin_amdgcn_update_dpp(0, __float_as_int(v), 0x143, 0xc, 0xf, true)); // bcast31
    return v;
}

__device__ __forceinline__ unsigned f2bf(float f) {   // RNE float->bf16 bits
    unsigned u = __float_as_uint(f);
    return (u + 0x7FFFu + ((u >> 16) & 1u)) >> 16;
}

// ---------------- init: constant tables + nz-compacted pack tables + scalar zero ----------------
__global__ __launch_bounds__(1024) void k_init(float* __restrict__ ws,
                                               float* __restrict__ out) {
    __shared__ float red[1024];
    __shared__ float lriS[640];
    __shared__ int   nzf[512];
    __shared__ int   wcnt[16];
    const int t = threadIdx.x;
    const int lane = t & 63, wvi = t >> 6;

    if (t == 0) out[2 * LTOT] = 0.f;   // k_hebb atomicAdds into this

    float sre_raw = 0.f;
    if (t < 25) {
        int u = t / 5, v = t % 5;
        double d = sqrt((double)((u-2)*(u-2) + (v-2)*(v-2)));
        if (d < 2.5) { double cv = cos(fmin(d/5.0, 1.0) * PI_D * 0.5); sre_raw = (float)(cv*cv); }
    }

    float lri_raw = 0.f;
    const int dy = t / 25, dx = t % 25;
    if (t < 625) {
        double d = sqrt((double)((dy-12)*(dy-12) + (dx-12)*(dx-12)));
        double base = 0.0, inh = 0.0;
        if (d < 12.5) { double cv = cos(fmin(d/25.0, 1.0) * PI_D * 0.5); base = cv*cv; }
        if (d < 1.25) { double cv = cos(fmin(d/2.5,  1.0) * PI_D * 0.5); inh  = cv*cv; }
        lri_raw = (float)(base * (1.0 - inh));
    }
    const bool nz = (lri_raw != 0.f);
    if (t < 640) lriS[t] = lri_raw;

    red[t] = lri_raw;
    __syncthreads();
    #pragma unroll
    for (int s = 512; s > 0; s >>= 1) {
        if (t < s) red[t] = fmaxf(red[t], red[t + s]);
        __syncthreads();
    }
    const float lri_max = red[0];
    __syncthreads();

    red[t] = sre_raw;
    __syncthreads();
    #pragma unroll
    for (int s = 512; s > 0; s >>= 1) {
        if (t < s) red[t] += red[t + s];
        __syncthreads();
    }
    const float sre_sum = red[0];

    if (t < 32) ws[WS_SRE + t] = (t < 25) ? sre_raw / sre_sum : 0.f;

    // ---- ballot prefix-scan -> compacted nonzero-lri list (488 entries) ----
    unsigned long long bal = __ballot(nz);
    if (lane == 0) wcnt[wvi] = __popcll(bal);
    __syncthreads();
    int woff = 0, ntot = 0;
    #pragma unroll
    for (int v2 = 0; v2 < 16; ++v2) { int c = wcnt[v2]; if (v2 < wvi) woff += c; ntot += c; }
    if (nz) nzf[woff + __popcll(bal & ((1ull << lane) - 1ull))] = t;
    __syncthreads();

    // pack tables: slot (2q+h)*64+lane <- nzf[2*(q*64+lane)+h]
    if (t < 256) {
        #pragma unroll
        for (int h = 0; h < 2; ++h) {
            int idx = 2*t + h;
            int f = 624, off = 0; float lv = 0.f;
            if (idx < ntot) {
                f = nzf[idx];
                int fy = f / 25, fx = f - 25*fy;
                off = fy * (2*EWH) + fx;
                lv = lriS[f] / lri_max;
            }
            int slot = (2*(t >> 6) + h)*64 + (t & 63);
            ((int*)  (ws + WS_PKF ))[slot] = f;
            ((float*)(ws + WS_PKL ))[slot] = lv;
            ((int*)  (ws + WS_OFFT))[slot] = off;
        }
    }

    // afferent table: {env, x offset}
    if (t < 512) {
        float ev = 0.f; int off = 0;
        if (t < 450) {
            int c  = t / 225, rr = t % 225;
            int kh = rr / 15, kw = rr % 15;
            double d = sqrt((double)((kh-7)*(kh-7) + (kw-7)*(kw-7)));
            if (d < 7.5) { double cv = cos(fmin(d/15.0, 1.0) * PI_D * 0.5); ev = (float)(cv*cv); }
            off = c * (IN_HW*IN_HW) + kh * IN_HW + kw;
        }
        ((float2*)(ws + WS_AFFTAB))[t] = make_float2(ev, __int_as_float(off));
    }
}

// ---------------- pre-pass: float4-staged streaming, 20KB LDS -> 8 blocks/CU ----------------
// blocks [0, NABLK): afferent (rfs).  blocks [NABLK, 2*NABLK): latw pack.
__global__ __launch_bounds__(PBLK, 8) void k_pre(const float* __restrict__ x,
                                                 const float* __restrict__ rfs,
                                                 const float* __restrict__ latw,
                                                 const float* __restrict__ ada,
                                                 float* __restrict__ out_rawaff,
                                                 float* __restrict__ ws,
                                                 unsigned* __restrict__ wq) {
    __shared__ __align__(16) float S[5008];    // 20 KB: pack 5000, aff 3600
    const int tid = threadIdx.x;
    const int w = tid >> 6, lane = tid & 63;

    if (blockIdx.x < NABLK) {
        // ---- afferent role: stage 8 rows of rfs (900 float4, 4 indep loads/thread) ----
        const int l0 = blockIdx.x * RPB;
        const f32x4* src4 = (const f32x4*)(rfs + (size_t)l0 * F_AFF);
        #pragma unroll
        for (int k = 0; k < 4; ++k) {
            int idx = k * PBLK + tid;
            if (idx < 900) ((f32x4*)S)[idx] = __builtin_nontemporal_load(src4 + idx);
        }

        // hoist afferent table into regs (shared across the wave's 2 rows)
        float envA[8]; int offA[8];
        const float2* atab = (const float2*)(ws + WS_AFFTAB);
        #pragma unroll
        for (int it = 0; it < 8; ++it) {
            float2 tb = atab[it*64 + lane];
            envA[it] = tb.x; offA[it] = __float_as_int(tb.y);
        }
        __syncthreads();

        #pragma unroll
        for (int s = 0; s < 2; ++s) {
            const int row = 2*w + s, l = l0 + row;
            const int i = l / SHEET, j = l % SHEET;
            const int xbase = i * IN_HW + j;
            const float* Srow = S + row * F_AFF;
            float dot = 0.f, rs = 0.f;
            #pragma unroll
            for (int it = 0; it < 8; ++it) {
                int f = it*64 + lane;
                float r = (f < F_AFF) ? Srow[f] : 0.f;
                float xv = x[xbase + offA[it]];
                dot = fmaf(xv * envA[it], r, dot);
                rs += r;
            }
            dot = wred_dpp(dot); rs = wred_dpp(rs);
            if (lane == 63) {
                float a = dot / rs;
                out_rawaff[l] = 45.0f * a;             // raw_aff
                float aff = a - ada[l];
                ws[WS_AFF + l] = aff;
                ws[WS_B0  + l] = fmaxf(aff, 0.f);      // lat_0 = relu(aff)
                ws[WS_LM  + l] = 0.f;
            }
        }
    } else {
        // ---- pack role: stage 8 rows of latw (1250 float4, 5 indep loads/thread) ----
        const int l0 = (blockIdx.x - NABLK) * RPB;
        const f32x4* src4 = (const f32x4*)(latw + (size_t)l0 * F_LAT);
        #pragma unroll
        for (int k = 0; k < 5; ++k) {
            int idx = k * PBLK + tid;
            if (idx < 1250) ((f32x4*)S)[idx] = __builtin_nontemporal_load(src4 + idx);
        }

        // hoist pack tables into regs
        int pf[8]; float pl[8];
        #pragma unroll
        for (int q8 = 0; q8 < 8; ++q8) {
            pf[q8] = ((const int*)  (ws + WS_PKF))[q8*64 + lane];
            pl[q8] = ((const float*)(ws + WS_PKL))[q8*64 + lane];
        }
        __syncthreads();

        #pragma unroll
        for (int s = 0; s < 2; ++s) {
            const int row = 2*w + s, l = l0 + row;
            const float* Srow = S + row * F_LAT;
            float sum = 0.f;
            #pragma unroll
            for (int it = 0; it < 10; ++it) {
                int f = it*64 + lane;
                sum += (f < F_LAT) ? Srow[f] : 0.f;
            }
            sum = wred_dpp(sum);
            const float inv = 1.0f / __int_as_float(__builtin_amdgcn_readlane(__float_as_int(sum), 63));
            unsigned* dst = wq + (size_t)l * NPAIR;
            #pragma unroll
            for (int q = 0; q < 4; ++q) {
                unsigned lo = f2bf(Srow[pf[2*q]]     * pl[2*q]     * inv);
                unsigned hi = f2bf(Srow[pf[2*q + 1]] * pl[2*q + 1] * inv);
                dst[q*64 + lane] = lo | (hi << 16);
            }
        }
    }
}

// ---------------- lateral iteration: 10x10 tile, grid 256 = 1 block/CU ----------------
__global__ __launch_bounds__(BLK, 3) void k_lat(const unsigned* __restrict__ wq,
                                                float* __restrict__ ws,
                                                const float* __restrict__ lsrc,
                                                float* __restrict__ lat_out) {
    __shared__ float Lt[LT_N];
    __shared__ float Ep[EP_N];
    const int b  = blockIdx.x;
    const int i0 = (b / TCOLS) * BH;
    const int j0 = (b % TCOLS) * BW;
    const int tid = threadIdx.x;
    const int w = tid >> 6, lane = tid & 63;
    const int lrow = (i0 + w) * SHEET + j0;        // wave w owns locs lrow+0..9

    // per-lane gather offsets (8 compacted slots)
    const int* offT = (const int*)(ws + WS_OFFT);
    int offr[8];
    #pragma unroll
    for (int q8 = 0; q8 < 8; ++q8) offr[q8] = offT[q8*64 + lane];

    // prefetch all 10 locations' packed weights (hidden under stage+conv)
    unsigned wp[10][4];
    #pragma unroll
    for (int s = 0; s < 10; ++s) {
        const unsigned* row = wq + (size_t)(lrow + s) * NPAIR;
        #pragma unroll
        for (int k = 0; k < 4; ++k) wp[s][k] = row[k*64 + lane];
    }
    __builtin_amdgcn_sched_barrier(0);

    // sre (uniform -> scalar loads)
    float sreg[25];
    #pragma unroll
    for (int q = 0; q < 25; ++q) sreg[q] = ws[WS_SRE + q];

    // ---- stage L tile (pad = HOMEO), 62 rows x 62 cols in [62][64] ----
    for (int idx = tid; idx < LT_N; idx += BLK) {
        int r = idx >> 6, c = idx & 63;
        int y  = i0 + r - 26;
        int xx = j0 + c - 26;
        float v = HOMEO;
        if (c < 62 && (unsigned)y < SHEET && (unsigned)xx < SHEET) v = lsrc[y*SHEET + xx];
        Lt[idx] = v;
    }
    __syncthreads();

    // ---- 5x5 conv -> E field 58x58 (4-wide register blocked, parity-split store) ----
    for (int qi = tid; qi < EH * 15; qi += BLK) {
        int y = qi / 15, q = qi - y * 15;
        int x0 = q * 4;
        float a0 = 0.f, a1 = 0.f, a2 = 0.f, a3 = 0.f;
        #pragma unroll
        for (int u = 0; u < 5; ++u) {
            const float* row = &Lt[(y + u) * LW + x0];
            float ra[8];
            #pragma unroll
            for (int v = 0; v < 8; ++v) ra[v] = row[v];
            #pragma unroll
            for (int v = 0; v < 5; ++v) {
                float s = sreg[u * 5 + v];
                a0 = fmaf(ra[v],     s, a0);
                a1 = fmaf(ra[v + 1], s, a1);
                a2 = fmaf(ra[v + 2], s, a2);
                a3 = fmaf(ra[v + 3], s, a3);
            }
        }
        int yg = i0 - 24 + y;
        bool yok = (unsigned)yg < SHEET;
        int xg = j0 - 24 + x0;
        float v0 = (yok && (unsigned)(xg    ) < SHEET) ? a0 : HOMEO;
        float v1 = (yok && (unsigned)(xg + 1) < SHEET) ? a1 : HOMEO;
        float v2 = (yok && (unsigned)(xg + 2) < SHEET) ? a2 : HOMEO;
        float v3 = (yok && (unsigned)(xg + 3) < SHEET) ? a3 : HOMEO;
        int c0 = y * EWH + 2 * q;
        Ep[c0]               = v0;   // E cols 58/59 (q=14) land in the pad
        Ep[EP_HALF + c0]     = v1;   // slot (col 29) - never gathered
        Ep[c0 + 1]           = v2;
        Ep[EP_HALF + c0 + 1] = v3;
    }
    __syncthreads();

    // ---- per-location 625-dot from register-resident bf16 weights ----
    float acc[10];
    #pragma unroll
    for (int s = 0; s < 10; ++s) {
        const int gbase = (s & 1) * EP_HALF + w * EWH + (s >> 1);
        float a = 0.f;
        #pragma unroll
        for (int k = 0; k < 4; ++k) {
            unsigned p = wp[s][k];
            float e0 = Ep[gbase + offr[2*k]];
            float e1 = Ep[gbase + offr[2*k + 1]];
            a = fmaf(e0, __uint_as_float(p << 16),         a);
            a = fmaf(e1, __uint_as_float(p & 0xffff0000u), a);
        }
        acc[s] = a;
    }
    #pragma unroll
    for (int s = 0; s < 10; ++s) acc[s] = wred_dpp(acc[s]);

    // broadcast acc[s] to lane s; lanes 0-9 finish their locations in parallel
    float accs = 0.f;
    #pragma unroll
    for (int s = 0; s < 10; ++s) {
        float a = __int_as_float(__builtin_amdgcn_readlane(__float_as_int(acc[s]), 63));
        if (lane == s) accs = a;
    }
    if (lane < 10) {
        int s = lane;
        int l = lrow + s;
        int gbase = (s & 1) * EP_HALF + w * EWH + (s >> 1);
        float ec = Ep[gbase + 24*EWH + 12];
        float v = ec * 0.45f - accs * 0.55f + ws[WS_AFF + l];
        v = tanhf(fmaxf(v, 0.f));
        lat_out[l] = v;
        ws[WS_LM + l] += v;
    }
}

// ---------------- hebbian correlation: same 10x10 tiling, no conv, atomic sum ----------------
__global__ __launch_bounds__(BLK, 3) void k_hebb(const unsigned* __restrict__ wq,
                                                 float* __restrict__ ws,
                                                 float* __restrict__ out_scalar) {
    __shared__ float LMp[EP_N];
    __shared__ float part[10];
    const int b  = blockIdx.x;
    const int i0 = (b / TCOLS) * BH;
    const int j0 = (b % TCOLS) * BW;
    const int tid = threadIdx.x;
    const int w = tid >> 6, lane = tid & 63;
    const int lrow = (i0 + w) * SHEET + j0;
    const float* lm = ws + WS_LM;

    const int* offT = (const int*)(ws + WS_OFFT);
    int offr[8];
    #pragma unroll
    for (int q8 = 0; q8 < 8; ++q8) offr[q8] = offT[q8*64 + lane];

    unsigned wp[10][4];
    #pragma unroll
    for (int s = 0; s < 10; ++s) {
        const unsigned* row = wq + (size_t)(lrow + s) * NPAIR;
        #pragma unroll
        for (int k = 0; k < 4; ++k) wp[s][k] = row[k*64 + lane];
    }
    __builtin_amdgcn_sched_barrier(0);

    // stage lat_mean tile (x0.1, pad HOMEO), parity-split 58x58
    for (int idx = tid; idx < EP_N; idx += BLK) {
        int p   = idx / EP_HALF;
        int rem = idx - p * EP_HALF;
        int y   = rem / EWH;
        int col = rem - y * EWH;
        int yg = i0 - 24 + y;
        int xg = j0 - 24 + 2 * col + p;
        float v = HOMEO;
        if ((unsigned)yg < SHEET && (unsigned)xg < SHEET && col < 29) v = lm[yg*SHEET + xg] * 0.1f;
        LMp[idx] = v;
    }
    __syncthreads();

    float acc[10];
    #pragma unroll
    for (int s = 0; s < 10; ++s) {
        const int gbase = (s & 1) * EP_HALF + w * EWH + (s >> 1);
        float a = 0.f;
        #pragma unroll
        for (int k = 0; k < 4; ++k) {
            unsigned p = wp[s][k];
            float e0 = LMp[gbase + offr[2*k]];
            float e1 = LMp[gbase + offr[2*k + 1]];
            a = fmaf(e0, __uint_as_float(p << 16),         a);
            a = fmaf(e1, __uint_as_float(p & 0xffff0000u), a);
        }
        acc[s] = a;
    }
    #pragma unroll
    for (int s = 0; s < 10; ++s) acc[s] = wred_dpp(acc[s]);

    if (lane == 63) {
        float wacc = 0.f;
        #pragma unroll
        for (int s = 0; s < 10; ++s) {
            int gbase = (s & 1) * EP_HALF + w * EWH + (s >> 1);
            float lmv = LMp[gbase + 24*EWH + 12];      // lat_mean[l] * 0.1
            wacc += lmv * 62.5f * acc[s];
        }
        part[w] = wacc;
    }
    __syncthreads();
    if (tid == 0) {
        float s = 0.f;
        #pragma unroll
        for (int q = 0; q < 10; ++q) s += part[q];
        atomicAdd(out_scalar, s);
    }
}

extern "C" void kernel_launch(void* const* d_in, const int* in_sizes, int n_in,
                              void* d_out, int out_size, void* d_ws, size_t ws_size,
                              hipStream_t stream) {
    const float* x    = (const float*)d_in[0];
    const float* rfs  = (const float*)d_in[1];
    const float* latw = (const float*)d_in[2];
    const float* ada  = (const float*)d_in[3];
    float* out = (float*)d_out;
    float* ws  = (float*)d_ws;
    unsigned* wq = (unsigned*)(ws + WS_WQ);

    k_init<<<1, 1024, 0, stream>>>(ws, out);
    k_pre<<<2 * NABLK, PBLK, 0, stream>>>(x, rfs, latw, ada, out, ws, wq);

    for (int t = 0; t < N_ITERS; ++t) {
        const float* src = ws + ((t & 1) ? WS_B1 : WS_B0);
        float* dst = (t == N_ITERS - 1) ? (out + LTOT)
                                        : (ws + ((t & 1) ? WS_B0 : WS_B1));
        k_lat<<<GRID_L, BLK, 0, stream>>>(wq, ws, src, dst);
    }

    k_hebb<<<GRID_L, BLK, 0, stream>>>(wq, ws, out + 2 * LTOT);
}